// Round 10
// baseline (700.787 us; speedup 1.0000x reference)
//
#include <hip/hip_runtime.h>

// MoE top-2, E=8, T=8192, H=1024, I=2816. bf16 MFMA grouped-GEMM pipeline.
// R10: down re-tiled BM128/BN256 (4 waves, wave-tile 64x128) -> half the
//      block-K-steps (45k -> 22.5k); per-K-step economics now match gateup
//      (64 MFMA + 12 GLD16 per wave). Split-K removed. Gateup R2-exact.

#define T_TOK 8192
#define H_DIM 1024
#define I_DIM 2816
#define NEXP  8
#define CAP   8192

typedef short bf16x8 __attribute__((ext_vector_type(8)));
typedef float f32x4  __attribute__((ext_vector_type(4)));

static __device__ __forceinline__ unsigned short f2bf(float f) {
  unsigned u = __float_as_uint(f);
  u = u + 0x7fffu + ((u >> 16) & 1u);   // RNE
  return (unsigned short)(u >> 16);
}

#define MFMA16x16x32(acc, a, b) \
  asm("v_mfma_f32_16x16x32_bf16 %0, %1, %2, %0" : "+v"(acc) : "v"(a), "v"(b))

#define GLD16(g, l) \
  __builtin_amdgcn_global_load_lds((const __attribute__((address_space(1))) void*)(g), \
                                   (__attribute__((address_space(3))) void*)(l), 16, 0, 0)

// ---------------- router: logits, top-2 softmax, expert lists, x->bf16 ----------------
__global__ __launch_bounds__(256) void router_kernel(
    const float* __restrict__ x, const float* __restrict__ wr,
    int* __restrict__ cnt, int* __restrict__ tokL, float* __restrict__ wgtL,
    unsigned short* __restrict__ xb) {
  __shared__ float rw[NEXP * H_DIM];    // 32 KB
  int tid = threadIdx.x;
#pragma unroll
  for (int it = 0; it < 8; ++it) {
    int i4 = it * 256 + tid;
    ((float4*)rw)[i4] = ((const float4*)wr)[i4];
  }
  __syncthreads();
  int wid = tid >> 6, lane = tid & 63;
  int t = blockIdx.x * 4 + wid;         // one wave per token
  float a[NEXP];
#pragma unroll
  for (int e = 0; e < NEXP; ++e) a[e] = 0.f;
#pragma unroll
  for (int hc = 0; hc < 4; ++hc) {
    int h = hc * 256 + lane * 4;
    float4 xv = *(const float4*)(x + (size_t)t * H_DIM + h);
    ushort4 o;
    o.x = f2bf(xv.x); o.y = f2bf(xv.y); o.z = f2bf(xv.z); o.w = f2bf(xv.w);
    *(ushort4*)(xb + (size_t)t * H_DIM + h) = o;
#pragma unroll
    for (int e = 0; e < NEXP; ++e) {
      float4 w4 = *(const float4*)(&rw[e * H_DIM + h]);
      a[e] += xv.x * w4.x + xv.y * w4.y + xv.z * w4.z + xv.w * w4.w;
    }
  }
#pragma unroll
  for (int e = 0; e < NEXP; ++e) {
    float v = a[e];
    for (int off = 32; off > 0; off >>= 1) v += __shfl_xor(v, off, 64);
    a[e] = v;
  }
  if (lane == 0) {
    int e1 = 0; float l1 = a[0];
#pragma unroll
    for (int e = 1; e < NEXP; ++e) if (a[e] > l1) { l1 = a[e]; e1 = e; }
    int e2 = -1; float l2 = -3.4e38f;
#pragma unroll
    for (int e = 0; e < NEXP; ++e) if (e != e1 && a[e] > l2) { l2 = a[e]; e2 = e; }
    float q = expf(l2 - l1);
    float w1 = 1.f / (1.f + q);
    float w2 = q * w1;
    int p1 = atomicAdd(&cnt[e1], 1);
    tokL[e1 * CAP + p1] = t; wgtL[e1 * CAP + p1] = w1;
    int p2 = atomicAdd(&cnt[e2], 1);
    tokL[e2 * CAP + p2] = t; wgtL[e2 * CAP + p2] = w2;
  }
}

__global__ void scan_kernel(const int* __restrict__ cnt, int* __restrict__ offs) {
  if (threadIdx.x == 0) {
    int s = 0;
    for (int e = 0; e < NEXP; ++e) { offs[e] = s; s += cnt[e]; }
  }
}

// ---------------- fused gate+up transpose: [8][1024][2816] f32 -> [8][2816][1024] bf16 x2 ----------------
__global__ __launch_bounds__(256) void transposeGU_kernel(
    const float* __restrict__ s1, const float* __restrict__ s2,
    unsigned short* __restrict__ d1, unsigned short* __restrict__ d2) {
  __shared__ float tile[64][65];
  int z = blockIdx.z;
  int m = z & 7;
  const float* src = (z < 8) ? s1 : s2;
  unsigned short* dst = (z < 8) ? d1 : d2;
  const int R = H_DIM, C = I_DIM;
  int r0 = blockIdx.y * 64, c0 = blockIdx.x * 64;
  const float* s = src + (size_t)m * R * C;
  unsigned short* d = dst + (size_t)m * R * C;
  int tid = threadIdx.x;
#pragma unroll
  for (int it = 0; it < 4; ++it) {
    int id4 = it * 256 + tid;
    int r = id4 >> 4, c4 = (id4 & 15) * 4;
    float4 v = *(const float4*)(s + (size_t)(r0 + r) * C + c0 + c4);
    tile[r][c4] = v.x; tile[r][c4 + 1] = v.y; tile[r][c4 + 2] = v.z; tile[r][c4 + 3] = v.w;
  }
  __syncthreads();
#pragma unroll
  for (int it = 0; it < 4; ++it) {
    int qd = it * 256 + tid;
    int c = qd >> 4, rq = (qd & 15) * 4;
    ushort4 o;
    o.x = f2bf(tile[rq][c]);     o.y = f2bf(tile[rq + 1][c]);
    o.z = f2bf(tile[rq + 2][c]); o.w = f2bf(tile[rq + 3][c]);
    *(ushort4*)(d + (size_t)(c0 + c) * R + r0 + rq) = o;
  }
}

// ---------------- generic transpose (for w_down) ----------------
__global__ __launch_bounds__(256) void transpose_kernel(
    const float* __restrict__ src, unsigned short* __restrict__ dst, int R, int C) {
  __shared__ float tile[64][65];
  int m = blockIdx.z;
  int r0 = blockIdx.y * 64, c0 = blockIdx.x * 64;
  const float* s = src + (size_t)m * R * C;
  unsigned short* d = dst + (size_t)m * R * C;
  int tid = threadIdx.x;
#pragma unroll
  for (int it = 0; it < 4; ++it) {
    int id4 = it * 256 + tid;
    int r = id4 >> 4, c4 = (id4 & 15) * 4;
    float4 v = *(const float4*)(s + (size_t)(r0 + r) * C + c0 + c4);
    tile[r][c4] = v.x; tile[r][c4 + 1] = v.y; tile[r][c4 + 2] = v.z; tile[r][c4 + 3] = v.w;
  }
  __syncthreads();
#pragma unroll
  for (int it = 0; it < 4; ++it) {
    int qd = it * 256 + tid;
    int c = qd >> 4, rq = (qd & 15) * 4;
    ushort4 o;
    o.x = f2bf(tile[rq][c]);     o.y = f2bf(tile[rq + 1][c]);
    o.z = f2bf(tile[rq + 2][c]); o.w = f2bf(tile[rq + 3][c]);
    *(ushort4*)(d + (size_t)(c0 + c) * R + r0 + rq) = o;
  }
}

// ---------------- gate+up fused grouped GEMM + silu*mul -> h (bf16) ----------------
// R2-exact structure. LDS linear [128][64] bf16; physical (row,c16) holds logical
// (row, c16^(row&7)); staged via GLD16 with pre-swizzled global source col.
__global__ __launch_bounds__(256) void gateup_kernel(
    const unsigned short* __restrict__ xb,
    const unsigned short* __restrict__ wgT,   // [E][I][H] bf16
    const unsigned short* __restrict__ wuT,
    const int* __restrict__ cnt, const int* __restrict__ offs,
    const int* __restrict__ tokL,
    unsigned short* __restrict__ hbuf) {
  int e = blockIdx.z;
  int cnt_e = cnt[e];
  int m0 = blockIdx.y * 128;
  if (m0 >= cnt_e) return;
  int n0 = blockIdx.x * 128;
  int rcnt = cnt_e - m0; if (rcnt > 128) rcnt = 128;

  __shared__ unsigned short As[128 * 64], Gs[128 * 64], Us[128 * 64];  // 48 KB
  __shared__ int trow[128];
  int tid = threadIdx.x;
  if (tid < 128) trow[tid] = tokL[e * CAP + m0 + ((tid < rcnt) ? tid : 0)];
  __syncthreads();

  int lane = tid & 63, wid = tid >> 6;
  int lr = lane >> 3;
  int csrc = ((lane & 7) ^ lr) * 8;          // pre-swizzled source col (shorts)

  const unsigned short* baseA[4];
  const unsigned short* baseG[4];
  const unsigned short* baseU[4];
  int ldso[4];
#pragma unroll
  for (int i = 0; i < 4; ++i) {
    int chunk = i * 4 + wid;
    int row = chunk * 8 + lr;
    baseA[i] = xb + (size_t)trow[row] * H_DIM + csrc;
    size_t wrow = ((size_t)e * I_DIM + n0 + row) * H_DIM + csrc;
    baseG[i] = wgT + wrow;
    baseU[i] = wuT + wrow;
    ldso[i] = chunk * 512;
  }

  int wr = wid >> 1, wc = wid & 1;
  int fr = lane & 15, fg = lane >> 4;
  int fsw = fr & 7;

  f32x4 accg[4][4], accu[4][4];
#pragma unroll
  for (int m = 0; m < 4; ++m)
#pragma unroll
    for (int n = 0; n < 4; ++n) { accg[m][n] = (f32x4)0.f; accu[m][n] = (f32x4)0.f; }

  for (int ks = 0; ks < H_DIM / 64; ++ks) {
    int k0 = ks * 64;
#pragma unroll
    for (int i = 0; i < 4; ++i) {
      GLD16(baseA[i] + k0, As + ldso[i]);
      GLD16(baseG[i] + k0, Gs + ldso[i]);
      GLD16(baseU[i] + k0, Us + ldso[i]);
    }
    __syncthreads();
#pragma unroll
    for (int kk = 0; kk < 2; ++kk) {
      int cb = ((kk * 4 + fg) ^ fsw) * 8;
      bf16x8 am[4], bg[4], bu[4];
#pragma unroll
      for (int m = 0; m < 4; ++m)
        am[m] = *(const bf16x8*)(As + (wr * 64 + m * 16 + fr) * 64 + cb);
#pragma unroll
      for (int n = 0; n < 4; ++n) {
        bg[n] = *(const bf16x8*)(Gs + (wc * 64 + n * 16 + fr) * 64 + cb);
        bu[n] = *(const bf16x8*)(Us + (wc * 64 + n * 16 + fr) * 64 + cb);
      }
#pragma unroll
      for (int m = 0; m < 4; ++m)
#pragma unroll
        for (int n = 0; n < 4; ++n) {
          MFMA16x16x32(accg[m][n], am[m], bg[n]);
          MFMA16x16x32(accu[m][n], am[m], bu[n]);
        }
    }
    __syncthreads();
  }
  int hb = offs[e];
#pragma unroll
  for (int m = 0; m < 4; ++m)
#pragma unroll
    for (int q = 0; q < 4; ++q) {
      int row = wr * 64 + m * 16 + fg * 4 + q;
      if (row < rcnt) {
        size_t rbase = (size_t)(hb + m0 + row) * I_DIM + n0 + wc * 64;
#pragma unroll
        for (int n = 0; n < 4; ++n) {
          float g = accg[m][n][q], u = accu[m][n][q];
          hbuf[rbase + n * 16 + fr] = f2bf(g / (1.f + expf(-g)) * u);
        }
      }
    }
}

// ---------------- down grouped GEMM BM128/BN256 + weighted atomic scatter-add ----------------
// 4 waves as 2M x 2N; wave-tile 64 x 128; 64 MFMA + 12 GLD16 per wave per K-step.
__global__ __launch_bounds__(256) void down_kernel(
    const unsigned short* __restrict__ hbuf,
    const unsigned short* __restrict__ wdT,   // [E][H][I] bf16
    const int* __restrict__ cnt, const int* __restrict__ offs,
    const int* __restrict__ tokL, const float* __restrict__ wgtL,
    float* __restrict__ out) {
  int e = blockIdx.z;
  int cnt_e = cnt[e];
  int m0 = blockIdx.y * 128;
  if (m0 >= cnt_e) return;
  int n0 = blockIdx.x * 256;
  int rcnt = cnt_e - m0; if (rcnt > 128) rcnt = 128;
  int hb = offs[e];

  __shared__ unsigned short As[128 * 64], Bs[256 * 64];   // 48 KB
  int tid = threadIdx.x, lane = tid & 63, wid = tid >> 6;
  int lr = lane >> 3;
  int csrc = ((lane & 7) ^ lr) * 8;

  const unsigned short* baseA[4];
  const unsigned short* baseB[8];
  int ldsoA[4], ldsoB[8];
#pragma unroll
  for (int i = 0; i < 4; ++i) {
    int chunk = i * 4 + wid;                  // 16 chunks cover 128 A rows
    int row = chunk * 8 + lr;
    int rowc = (row < rcnt) ? row : (rcnt - 1);           // clamp: stay in-expert
    baseA[i] = hbuf + (size_t)(hb + m0 + rowc) * I_DIM + csrc;
    ldsoA[i] = chunk * 512;
  }
#pragma unroll
  for (int i = 0; i < 8; ++i) {
    int chunk = i * 4 + wid;                  // 32 chunks cover 256 B rows
    int row = chunk * 8 + lr;
    baseB[i] = wdT + ((size_t)e * H_DIM + n0 + row) * I_DIM + csrc;
    ldsoB[i] = chunk * 512;
  }

  int wr = wid >> 1, wc = wid & 1, fr = lane & 15, fg = lane >> 4;
  int fsw = fr & 7;

  f32x4 acc[4][8];
#pragma unroll
  for (int m = 0; m < 4; ++m)
#pragma unroll
    for (int n = 0; n < 8; ++n) acc[m][n] = (f32x4)0.f;

  for (int ks = 0; ks < I_DIM / 64; ++ks) {   // 44 K-steps
    int k0 = ks * 64;
#pragma unroll
    for (int i = 0; i < 4; ++i) GLD16(baseA[i] + k0, As + ldsoA[i]);
#pragma unroll
    for (int i = 0; i < 8; ++i) GLD16(baseB[i] + k0, Bs + ldsoB[i]);
    __syncthreads();
#pragma unroll
    for (int kk = 0; kk < 2; ++kk) {
      int cb = ((kk * 4 + fg) ^ fsw) * 8;
      bf16x8 am[4], bn[8];
#pragma unroll
      for (int m = 0; m < 4; ++m)
        am[m] = *(const bf16x8*)(As + (wr * 64 + m * 16 + fr) * 64 + cb);
#pragma unroll
      for (int n = 0; n < 8; ++n)
        bn[n] = *(const bf16x8*)(Bs + (wc * 128 + n * 16 + fr) * 64 + cb);
#pragma unroll
      for (int m = 0; m < 4; ++m)
#pragma unroll
        for (int n = 0; n < 8; ++n)
          MFMA16x16x32(acc[m][n], am[m], bn[n]);
    }
    __syncthreads();
  }
#pragma unroll
  for (int m = 0; m < 4; ++m)
#pragma unroll
    for (int q = 0; q < 4; ++q) {
      int row = wr * 64 + m * 16 + fg * 4 + q;
      if (row < rcnt) {
        float w = wgtL[e * CAP + m0 + row];
        int t = tokL[e * CAP + m0 + row];
        float* obase = out + (size_t)t * H_DIM + n0 + wc * 128;
#pragma unroll
        for (int n = 0; n < 8; ++n)
          atomicAdd(obase + n * 16 + fr, w * acc[m][n][q]);
      }
    }
}

extern "C" void kernel_launch(void* const* d_in, const int* in_sizes, int n_in,
                              void* d_out, int out_size, void* d_ws, size_t ws_size,
                              hipStream_t stream) {
  const float* x   = (const float*)d_in[0];
  const float* wr  = (const float*)d_in[1];
  const float* wg  = (const float*)d_in[2];
  const float* wu  = (const float*)d_in[3];
  const float* wd  = (const float*)d_in[4];
  float* out = (float*)d_out;

  char* ws = (char*)d_ws;
  int*   cnt  = (int*)ws;
  int*   offs = (int*)(ws + 64);
  int*   tokL = (int*)(ws + 1024);
  float* wgtL = (float*)(ws + 1024 + (size_t)NEXP * CAP * 4);
  unsigned short* xb  = (unsigned short*)(ws + (1u << 20));
  unsigned short* wgT = (unsigned short*)(ws + (1u << 20) + (size_t)T_TOK * H_DIM * 2);
  unsigned short* wuT = wgT + (size_t)NEXP * I_DIM * H_DIM;
  unsigned short* wdT = wuT + (size_t)NEXP * I_DIM * H_DIM;
  unsigned short* hbuf = wdT + (size_t)NEXP * H_DIM * I_DIM;

  hipMemsetAsync(ws, 0, 64, stream);                        // counts
  hipMemsetAsync(d_out, 0, (size_t)out_size * 4, stream);   // atomics accumulate

  router_kernel<<<T_TOK / 4, 256, 0, stream>>>(x, wr, cnt, tokL, wgtL, xb);
  scan_kernel<<<1, 64, 0, stream>>>(cnt, offs);

  transposeGU_kernel<<<dim3(I_DIM / 64, H_DIM / 64, 16), 256, 0, stream>>>(wg, wu, wgT, wuT);
  transpose_kernel<<<dim3(H_DIM / 64, I_DIM / 64, NEXP), 256, 0, stream>>>(wd, wdT, I_DIM, H_DIM);

  gateup_kernel<<<dim3(I_DIM / 128, CAP / 128, NEXP), 256, 0, stream>>>(
      xb, wgT, wuT, cnt, offs, tokL, hbuf);
  down_kernel<<<dim3(H_DIM / 256, CAP / 128, NEXP), 256, 0, stream>>>(
      hbuf, wdT, cnt, offs, tokL, wgtL, out);
}

// Round 11
// 693.803 us; speedup vs baseline: 1.0101x; 1.0101x over previous
//
#include <hip/hip_runtime.h>

// MoE top-2, E=8, T=8192, H=1024, I=2816. bf16 MFMA grouped-GEMM pipeline.
// R11: measurement round. R8-exact config (best: down -> y bf16 stores + combine,
//      no atomics, no out memset). Gateup split into two n-half dispatches so the
//      top-5 profiler table reveals the true duration of down/transposes.

#define T_TOK 8192
#define H_DIM 1024
#define I_DIM 2816
#define NEXP  8
#define CAP   8192

typedef short bf16x8 __attribute__((ext_vector_type(8)));
typedef float f32x4  __attribute__((ext_vector_type(4)));

static __device__ __forceinline__ unsigned short f2bf(float f) {
  unsigned u = __float_as_uint(f);
  u = u + 0x7fffu + ((u >> 16) & 1u);   // RNE
  return (unsigned short)(u >> 16);
}
static __device__ __forceinline__ float bf2f(unsigned short u) {
  unsigned v = ((unsigned)u) << 16;
  return __uint_as_float(v);
}

#define MFMA16x16x32(acc, a, b) \
  asm("v_mfma_f32_16x16x32_bf16 %0, %1, %2, %0" : "+v"(acc) : "v"(a), "v"(b))

#define GLD16(g, l) \
  __builtin_amdgcn_global_load_lds((const __attribute__((address_space(1))) void*)(g), \
                                   (__attribute__((address_space(3))) void*)(l), 16, 0, 0)

// ---------------- router: logits, top-2 softmax, expert lists + token->slot map ----------------
__global__ __launch_bounds__(256) void router_kernel(
    const float* __restrict__ x, const float* __restrict__ wr,
    int* __restrict__ cnt, int* __restrict__ tokL,
    int* __restrict__ sA, int* __restrict__ sB,
    float* __restrict__ wA, float* __restrict__ wB,
    unsigned short* __restrict__ xb) {
  __shared__ float rw[NEXP * H_DIM];    // 32 KB
  int tid = threadIdx.x;
#pragma unroll
  for (int it = 0; it < 8; ++it) {
    int i4 = it * 256 + tid;
    ((float4*)rw)[i4] = ((const float4*)wr)[i4];
  }
  __syncthreads();
  int wid = tid >> 6, lane = tid & 63;
  int t = blockIdx.x * 4 + wid;         // one wave per token
  float a[NEXP];
#pragma unroll
  for (int e = 0; e < NEXP; ++e) a[e] = 0.f;
#pragma unroll
  for (int hc = 0; hc < 4; ++hc) {
    int h = hc * 256 + lane * 4;
    float4 xv = *(const float4*)(x + (size_t)t * H_DIM + h);
    ushort4 o;
    o.x = f2bf(xv.x); o.y = f2bf(xv.y); o.z = f2bf(xv.z); o.w = f2bf(xv.w);
    *(ushort4*)(xb + (size_t)t * H_DIM + h) = o;
#pragma unroll
    for (int e = 0; e < NEXP; ++e) {
      float4 w4 = *(const float4*)(&rw[e * H_DIM + h]);
      a[e] += xv.x * w4.x + xv.y * w4.y + xv.z * w4.z + xv.w * w4.w;
    }
  }
#pragma unroll
  for (int e = 0; e < NEXP; ++e) {
    float v = a[e];
    for (int off = 32; off > 0; off >>= 1) v += __shfl_xor(v, off, 64);
    a[e] = v;
  }
  if (lane == 0) {
    int e1 = 0; float l1 = a[0];
#pragma unroll
    for (int e = 1; e < NEXP; ++e) if (a[e] > l1) { l1 = a[e]; e1 = e; }
    int e2 = -1; float l2 = -3.4e38f;
#pragma unroll
    for (int e = 0; e < NEXP; ++e) if (e != e1 && a[e] > l2) { l2 = a[e]; e2 = e; }
    float q = expf(l2 - l1);
    float w1 = 1.f / (1.f + q);
    float w2 = q * w1;
    int p1 = atomicAdd(&cnt[e1], 1);
    tokL[e1 * CAP + p1] = t;
    int p2 = atomicAdd(&cnt[e2], 1);
    tokL[e2 * CAP + p2] = t;
    sA[t] = e1 * CAP + p1; wA[t] = w1;
    sB[t] = e2 * CAP + p2; wB[t] = w2;
  }
}

__global__ void scan_kernel(const int* __restrict__ cnt, int* __restrict__ offs) {
  if (threadIdx.x == 0) {
    int s = 0;
    for (int e = 0; e < NEXP; ++e) { offs[e] = s; s += cnt[e]; }
  }
}

// ---------------- fused gate+up transpose: [8][1024][2816] f32 -> [8][2816][1024] bf16 x2 ----------------
__global__ __launch_bounds__(256) void transposeGU_kernel(
    const float* __restrict__ s1, const float* __restrict__ s2,
    unsigned short* __restrict__ d1, unsigned short* __restrict__ d2) {
  __shared__ float tile[64][65];
  int z = blockIdx.z;
  int m = z & 7;
  const float* src = (z < 8) ? s1 : s2;
  unsigned short* dst = (z < 8) ? d1 : d2;
  const int R = H_DIM, C = I_DIM;
  int r0 = blockIdx.y * 64, c0 = blockIdx.x * 64;
  const float* s = src + (size_t)m * R * C;
  unsigned short* d = dst + (size_t)m * R * C;
  int tid = threadIdx.x;
#pragma unroll
  for (int it = 0; it < 4; ++it) {
    int id4 = it * 256 + tid;
    int r = id4 >> 4, c4 = (id4 & 15) * 4;
    float4 v = *(const float4*)(s + (size_t)(r0 + r) * C + c0 + c4);
    tile[r][c4] = v.x; tile[r][c4 + 1] = v.y; tile[r][c4 + 2] = v.z; tile[r][c4 + 3] = v.w;
  }
  __syncthreads();
#pragma unroll
  for (int it = 0; it < 4; ++it) {
    int qd = it * 256 + tid;
    int c = qd >> 4, rq = (qd & 15) * 4;
    ushort4 o;
    o.x = f2bf(tile[rq][c]);     o.y = f2bf(tile[rq + 1][c]);
    o.z = f2bf(tile[rq + 2][c]); o.w = f2bf(tile[rq + 3][c]);
    *(ushort4*)(d + (size_t)(c0 + c) * R + r0 + rq) = o;
  }
}

// ---------------- generic transpose (for w_down) ----------------
__global__ __launch_bounds__(256) void transpose_kernel(
    const float* __restrict__ src, unsigned short* __restrict__ dst, int R, int C) {
  __shared__ float tile[64][65];
  int m = blockIdx.z;
  int r0 = blockIdx.y * 64, c0 = blockIdx.x * 64;
  const float* s = src + (size_t)m * R * C;
  unsigned short* d = dst + (size_t)m * R * C;
  int tid = threadIdx.x;
#pragma unroll
  for (int it = 0; it < 4; ++it) {
    int id4 = it * 256 + tid;
    int r = id4 >> 4, c4 = (id4 & 15) * 4;
    float4 v = *(const float4*)(s + (size_t)(r0 + r) * C + c0 + c4);
    tile[r][c4] = v.x; tile[r][c4 + 1] = v.y; tile[r][c4 + 2] = v.z; tile[r][c4 + 3] = v.w;
  }
  __syncthreads();
#pragma unroll
  for (int it = 0; it < 4; ++it) {
    int qd = it * 256 + tid;
    int c = qd >> 4, rq = (qd & 15) * 4;
    ushort4 o;
    o.x = f2bf(tile[rq][c]);     o.y = f2bf(tile[rq + 1][c]);
    o.z = f2bf(tile[rq + 2][c]); o.w = f2bf(tile[rq + 3][c]);
    *(ushort4*)(d + (size_t)(c0 + c) * R + r0 + rq) = o;
  }
}

// ---------------- gate+up fused grouped GEMM + silu*mul -> h (bf16) ----------------
// R2-exact structure; n_base allows split dispatch (top-5 un-crowding).
__global__ __launch_bounds__(256) void gateup_kernel(
    const unsigned short* __restrict__ xb,
    const unsigned short* __restrict__ wgT,   // [E][I][H] bf16
    const unsigned short* __restrict__ wuT,
    const int* __restrict__ cnt, const int* __restrict__ offs,
    const int* __restrict__ tokL,
    unsigned short* __restrict__ hbuf, int n_base) {
  int e = blockIdx.z;
  int cnt_e = cnt[e];
  int m0 = blockIdx.y * 128;
  if (m0 >= cnt_e) return;
  int n0 = n_base + blockIdx.x * 128;
  int rcnt = cnt_e - m0; if (rcnt > 128) rcnt = 128;

  __shared__ unsigned short As[128 * 64], Gs[128 * 64], Us[128 * 64];  // 48 KB
  __shared__ int trow[128];
  int tid = threadIdx.x;
  if (tid < 128) trow[tid] = tokL[e * CAP + m0 + ((tid < rcnt) ? tid : 0)];
  __syncthreads();

  int lane = tid & 63, wid = tid >> 6;
  int lr = lane >> 3;
  int csrc = ((lane & 7) ^ lr) * 8;          // pre-swizzled source col (shorts)

  const unsigned short* baseA[4];
  const unsigned short* baseG[4];
  const unsigned short* baseU[4];
  int ldso[4];
#pragma unroll
  for (int i = 0; i < 4; ++i) {
    int chunk = i * 4 + wid;
    int row = chunk * 8 + lr;
    baseA[i] = xb + (size_t)trow[row] * H_DIM + csrc;
    size_t wrow = ((size_t)e * I_DIM + n0 + row) * H_DIM + csrc;
    baseG[i] = wgT + wrow;
    baseU[i] = wuT + wrow;
    ldso[i] = chunk * 512;
  }

  int wr = wid >> 1, wc = wid & 1;
  int fr = lane & 15, fg = lane >> 4;
  int fsw = fr & 7;

  f32x4 accg[4][4], accu[4][4];
#pragma unroll
  for (int m = 0; m < 4; ++m)
#pragma unroll
    for (int n = 0; n < 4; ++n) { accg[m][n] = (f32x4)0.f; accu[m][n] = (f32x4)0.f; }

  for (int ks = 0; ks < H_DIM / 64; ++ks) {
    int k0 = ks * 64;
#pragma unroll
    for (int i = 0; i < 4; ++i) {
      GLD16(baseA[i] + k0, As + ldso[i]);
      GLD16(baseG[i] + k0, Gs + ldso[i]);
      GLD16(baseU[i] + k0, Us + ldso[i]);
    }
    __syncthreads();
#pragma unroll
    for (int kk = 0; kk < 2; ++kk) {
      int cb = ((kk * 4 + fg) ^ fsw) * 8;
      bf16x8 am[4], bg[4], bu[4];
#pragma unroll
      for (int m = 0; m < 4; ++m)
        am[m] = *(const bf16x8*)(As + (wr * 64 + m * 16 + fr) * 64 + cb);
#pragma unroll
      for (int n = 0; n < 4; ++n) {
        bg[n] = *(const bf16x8*)(Gs + (wc * 64 + n * 16 + fr) * 64 + cb);
        bu[n] = *(const bf16x8*)(Us + (wc * 64 + n * 16 + fr) * 64 + cb);
      }
#pragma unroll
      for (int m = 0; m < 4; ++m)
#pragma unroll
        for (int n = 0; n < 4; ++n) {
          MFMA16x16x32(accg[m][n], am[m], bg[n]);
          MFMA16x16x32(accu[m][n], am[m], bu[n]);
        }
    }
    __syncthreads();
  }
  int hb = offs[e];
#pragma unroll
  for (int m = 0; m < 4; ++m)
#pragma unroll
    for (int q = 0; q < 4; ++q) {
      int row = wr * 64 + m * 16 + fg * 4 + q;
      if (row < rcnt) {
        size_t rbase = (size_t)(hb + m0 + row) * I_DIM + n0 + wc * 64;
#pragma unroll
        for (int n = 0; n < 4; ++n) {
          float g = accg[m][n][q], u = accu[m][n][q];
          hbuf[rbase + n * 16 + fr] = f2bf(g / (1.f + expf(-g)) * u);
        }
      }
    }
}

// ---------------- down grouped GEMM -> y[slot] (bf16, plain stores) ----------------
__global__ __launch_bounds__(256) void down_kernel(
    const unsigned short* __restrict__ hbuf,
    const unsigned short* __restrict__ wdT,   // [E][H][I] bf16
    const int* __restrict__ cnt, const int* __restrict__ offs,
    unsigned short* __restrict__ y) {         // [16384][H] bf16 compact rows
  int e = blockIdx.z;
  int cnt_e = cnt[e];
  int m0 = blockIdx.y * 128;
  if (m0 >= cnt_e) return;
  int n0 = blockIdx.x * 128;
  int rcnt = cnt_e - m0; if (rcnt > 128) rcnt = 128;
  int hb = offs[e];

  __shared__ unsigned short As[128 * 64], Bs[128 * 64];   // 32 KB
  int tid = threadIdx.x, lane = tid & 63, wid = tid >> 6;
  int lr = lane >> 3;
  int csrc = ((lane & 7) ^ lr) * 8;

  const unsigned short* baseA[4];
  const unsigned short* baseB[4];
  int ldso[4];
#pragma unroll
  for (int i = 0; i < 4; ++i) {
    int chunk = i * 4 + wid;
    int row = chunk * 8 + lr;
    int rowc = (row < rcnt) ? row : (rcnt - 1);           // clamp: stay in-expert
    baseA[i] = hbuf + (size_t)(hb + m0 + rowc) * I_DIM + csrc;
    baseB[i] = wdT + ((size_t)e * H_DIM + n0 + row) * I_DIM + csrc;
    ldso[i] = chunk * 512;
  }

  int wr = wid >> 1, wc = wid & 1, fr = lane & 15, fg = lane >> 4;
  int fsw = fr & 7;

  f32x4 acc[4][4];
#pragma unroll
  for (int m = 0; m < 4; ++m)
#pragma unroll
    for (int n = 0; n < 4; ++n) acc[m][n] = (f32x4)0.f;

  for (int ks = 0; ks < I_DIM / 64; ++ks) {   // 44 steps
    int k0 = ks * 64;
#pragma unroll
    for (int i = 0; i < 4; ++i) {
      GLD16(baseA[i] + k0, As + ldso[i]);
      GLD16(baseB[i] + k0, Bs + ldso[i]);
    }
    __syncthreads();
#pragma unroll
    for (int kk = 0; kk < 2; ++kk) {
      int cb = ((kk * 4 + fg) ^ fsw) * 8;
      bf16x8 am[4], bn[4];
#pragma unroll
      for (int m = 0; m < 4; ++m)
        am[m] = *(const bf16x8*)(As + (wr * 64 + m * 16 + fr) * 64 + cb);
#pragma unroll
      for (int n = 0; n < 4; ++n)
        bn[n] = *(const bf16x8*)(Bs + (wc * 64 + n * 16 + fr) * 64 + cb);
#pragma unroll
      for (int m = 0; m < 4; ++m)
#pragma unroll
        for (int n = 0; n < 4; ++n)
          MFMA16x16x32(acc[m][n], am[m], bn[n]);
    }
    __syncthreads();
  }
#pragma unroll
  for (int m = 0; m < 4; ++m)
#pragma unroll
    for (int q = 0; q < 4; ++q) {
      int row = wr * 64 + m * 16 + fg * 4 + q;
      if (row < rcnt) {
        size_t ybase = (size_t)(hb + m0 + row) * H_DIM + n0 + wc * 64;
#pragma unroll
        for (int n = 0; n < 4; ++n)
          y[ybase + n * 16 + fr] = f2bf(acc[m][n][q]);
      }
    }
}

// ---------------- gather-combine: out[t] = w1*y[c1] + w2*y[c2] ----------------
__global__ __launch_bounds__(256) void combine_kernel(
    const unsigned short* __restrict__ y, const int* __restrict__ offs,
    const int* __restrict__ sA, const int* __restrict__ sB,
    const float* __restrict__ wA, const float* __restrict__ wB,
    float* __restrict__ out) {
  int t = blockIdx.x;
  int s1 = sA[t], s2 = sB[t];
  float w1 = wA[t], w2 = wB[t];
  int c1 = offs[s1 >> 13] + (s1 & (CAP - 1));
  int c2 = offs[s2 >> 13] + (s2 & (CAP - 1));
  int h = threadIdx.x * 4;
  ushort4 a = *(const ushort4*)(y + (size_t)c1 * H_DIM + h);
  ushort4 b = *(const ushort4*)(y + (size_t)c2 * H_DIM + h);
  float4 o;
  o.x = w1 * bf2f(a.x) + w2 * bf2f(b.x);
  o.y = w1 * bf2f(a.y) + w2 * bf2f(b.y);
  o.z = w1 * bf2f(a.z) + w2 * bf2f(b.z);
  o.w = w1 * bf2f(a.w) + w2 * bf2f(b.w);
  *(float4*)(out + (size_t)t * H_DIM + h) = o;
}

extern "C" void kernel_launch(void* const* d_in, const int* in_sizes, int n_in,
                              void* d_out, int out_size, void* d_ws, size_t ws_size,
                              hipStream_t stream) {
  const float* x   = (const float*)d_in[0];
  const float* wr  = (const float*)d_in[1];
  const float* wg  = (const float*)d_in[2];
  const float* wu  = (const float*)d_in[3];
  const float* wd  = (const float*)d_in[4];
  float* out = (float*)d_out;

  char* ws = (char*)d_ws;
  int*   cnt  = (int*)ws;                                   // 32 B
  int*   offs = (int*)(ws + 64);
  int*   tokL = (int*)(ws + 1024);                          // 256 KB
  int*   sA   = (int*)(ws + 1024 + 262144);                 // 32 KB
  int*   sB   = (int*)(ws + 1024 + 262144 + 32768);
  float* wA   = (float*)(ws + 1024 + 262144 + 65536);
  float* wB   = (float*)(ws + 1024 + 262144 + 98304);
  unsigned short* xb  = (unsigned short*)(ws + (1u << 20));
  unsigned short* wgT = (unsigned short*)(ws + (1u << 20) + (size_t)T_TOK * H_DIM * 2);
  unsigned short* wuT = wgT + (size_t)NEXP * I_DIM * H_DIM;
  unsigned short* wdT = wuT + (size_t)NEXP * I_DIM * H_DIM;
  unsigned short* hbuf = wdT + (size_t)NEXP * H_DIM * I_DIM;
  unsigned short* y    = hbuf + (size_t)2 * T_TOK * I_DIM;

  hipMemsetAsync(ws, 0, 64, stream);                        // counts

  router_kernel<<<T_TOK / 4, 256, 0, stream>>>(x, wr, cnt, tokL, sA, sB, wA, wB, xb);
  scan_kernel<<<1, 64, 0, stream>>>(cnt, offs);

  transposeGU_kernel<<<dim3(I_DIM / 64, H_DIM / 64, 16), 256, 0, stream>>>(wg, wu, wgT, wuT);
  transpose_kernel<<<dim3(H_DIM / 64, I_DIM / 64, NEXP), 256, 0, stream>>>(wd, wdT, I_DIM, H_DIM);

  // split gateup into two n-halves (11 + 11 n-blocks) to un-crowd the profiler top-5
  gateup_kernel<<<dim3(11, CAP / 128, NEXP), 256, 0, stream>>>(
      xb, wgT, wuT, cnt, offs, tokL, hbuf, 0);
  gateup_kernel<<<dim3(11, CAP / 128, NEXP), 256, 0, stream>>>(
      xb, wgT, wuT, cnt, offs, tokL, hbuf, 11 * 128);
  down_kernel<<<dim3(H_DIM / 128, CAP / 128, NEXP), 256, 0, stream>>>(
      hbuf, wdT, cnt, offs, y);
  combine_kernel<<<T_TOK, 256, 0, stream>>>(y, offs, sA, sB, wA, wB, out);
}

// Round 12
// 521.467 us; speedup vs baseline: 1.3439x; 1.3305x over previous
//
#include <hip/hip_runtime.h>

// MoE top-2, E=8, T=8192, H=1024, I=2816. bf16 MFMA grouped-GEMM pipeline.
// R12: router rewrite — LDS-aggregated counting (8 atomics/block, 256 blocks)
//      replaces 32768 same-address atomicAdds (was 194us, serialized at L2).
//      Rest = R8/R11 best config: gateup R2-exact (single launch), down->y bf16,
//      gather-combine epilogue.

#define T_TOK 8192
#define H_DIM 1024
#define I_DIM 2816
#define NEXP  8
#define CAP   8192

typedef short bf16x8 __attribute__((ext_vector_type(8)));
typedef float f32x4  __attribute__((ext_vector_type(4)));

static __device__ __forceinline__ unsigned short f2bf(float f) {
  unsigned u = __float_as_uint(f);
  u = u + 0x7fffu + ((u >> 16) & 1u);   // RNE
  return (unsigned short)(u >> 16);
}
static __device__ __forceinline__ float bf2f(unsigned short u) {
  unsigned v = ((unsigned)u) << 16;
  return __uint_as_float(v);
}

#define MFMA16x16x32(acc, a, b) \
  asm("v_mfma_f32_16x16x32_bf16 %0, %1, %2, %0" : "+v"(acc) : "v"(a), "v"(b))

#define GLD16(g, l) \
  __builtin_amdgcn_global_load_lds((const __attribute__((address_space(1))) void*)(g), \
                                   (__attribute__((address_space(3))) void*)(l), 16, 0, 0)

// ---------------- router: 256 blocks x 32 tokens, LDS-aggregated counts ----------------
__global__ __launch_bounds__(256) void router_kernel(
    const float* __restrict__ x, const float* __restrict__ wr,
    int* __restrict__ cnt, int* __restrict__ tokL,
    int* __restrict__ sA, int* __restrict__ sB,
    float* __restrict__ wA, float* __restrict__ wB,
    unsigned short* __restrict__ xb) {
  __shared__ float rw[NEXP * H_DIM];    // 32 KB
  __shared__ int   selE[64];            // 32 tokens x 2
  __shared__ float selW[64];
  __shared__ int   rankL[64];
  __shared__ int   baseL[NEXP];
  int tid = threadIdx.x;
#pragma unroll
  for (int it = 0; it < 8; ++it) {
    int i4 = it * 256 + tid;
    ((float4*)rw)[i4] = ((const float4*)wr)[i4];
  }
  __syncthreads();
  int wid = tid >> 6, lane = tid & 63;
  int tbase = blockIdx.x * 32;

  for (int it = 0; it < 8; ++it) {      // 8 tokens per wave
    int tl = wid * 8 + it;              // local token 0..31
    int t = tbase + tl;
    float a[NEXP];
#pragma unroll
    for (int e = 0; e < NEXP; ++e) a[e] = 0.f;
#pragma unroll
    for (int hc = 0; hc < 4; ++hc) {
      int h = hc * 256 + lane * 4;
      float4 xv = *(const float4*)(x + (size_t)t * H_DIM + h);
      ushort4 o;
      o.x = f2bf(xv.x); o.y = f2bf(xv.y); o.z = f2bf(xv.z); o.w = f2bf(xv.w);
      *(ushort4*)(xb + (size_t)t * H_DIM + h) = o;
#pragma unroll
      for (int e = 0; e < NEXP; ++e) {
        float4 w4 = *(const float4*)(&rw[e * H_DIM + h]);
        a[e] += xv.x * w4.x + xv.y * w4.y + xv.z * w4.z + xv.w * w4.w;
      }
    }
#pragma unroll
    for (int e = 0; e < NEXP; ++e) {
      float v = a[e];
      for (int off = 32; off > 0; off >>= 1) v += __shfl_xor(v, off, 64);
      a[e] = v;
    }
    if (lane == 0) {
      int e1 = 0; float l1 = a[0];
#pragma unroll
      for (int e = 1; e < NEXP; ++e) if (a[e] > l1) { l1 = a[e]; e1 = e; }
      int e2 = -1; float l2 = -3.4e38f;
#pragma unroll
      for (int e = 0; e < NEXP; ++e) if (e != e1 && a[e] > l2) { l2 = a[e]; e2 = e; }
      float q = expf(l2 - l1);
      float w1 = 1.f / (1.f + q);
      selE[tl * 2]     = e1; selW[tl * 2]     = w1;
      selE[tl * 2 + 1] = e2; selW[tl * 2 + 1] = q * w1;
    }
  }
  __syncthreads();
  if (tid == 0) {                       // serial local count+rank (64 entries)
    int cl[NEXP];
#pragma unroll
    for (int e = 0; e < NEXP; ++e) cl[e] = 0;
    for (int i = 0; i < 64; ++i) rankL[i] = cl[selE[i]]++;
    for (int e = 0; e < NEXP; ++e)
      baseL[e] = cl[e] ? atomicAdd(&cnt[e], cl[e]) : 0;
  }
  __syncthreads();
  if (tid < 64) {                       // scatter
    int e = selE[tid];
    int p = baseL[e] + rankL[tid];
    int t = tbase + (tid >> 1);
    tokL[e * CAP + p] = t;
    int slot = e * CAP + p;
    if (tid & 1) { sB[t] = slot; wB[t] = selW[tid]; }
    else         { sA[t] = slot; wA[t] = selW[tid]; }
  }
}

__global__ void scan_kernel(const int* __restrict__ cnt, int* __restrict__ offs) {
  if (threadIdx.x == 0) {
    int s = 0;
    for (int e = 0; e < NEXP; ++e) { offs[e] = s; s += cnt[e]; }
  }
}

// ---------------- fused gate+up transpose: [8][1024][2816] f32 -> [8][2816][1024] bf16 x2 ----------------
__global__ __launch_bounds__(256) void transposeGU_kernel(
    const float* __restrict__ s1, const float* __restrict__ s2,
    unsigned short* __restrict__ d1, unsigned short* __restrict__ d2) {
  __shared__ float tile[64][65];
  int z = blockIdx.z;
  int m = z & 7;
  const float* src = (z < 8) ? s1 : s2;
  unsigned short* dst = (z < 8) ? d1 : d2;
  const int R = H_DIM, C = I_DIM;
  int r0 = blockIdx.y * 64, c0 = blockIdx.x * 64;
  const float* s = src + (size_t)m * R * C;
  unsigned short* d = dst + (size_t)m * R * C;
  int tid = threadIdx.x;
#pragma unroll
  for (int it = 0; it < 4; ++it) {
    int id4 = it * 256 + tid;
    int r = id4 >> 4, c4 = (id4 & 15) * 4;
    float4 v = *(const float4*)(s + (size_t)(r0 + r) * C + c0 + c4);
    tile[r][c4] = v.x; tile[r][c4 + 1] = v.y; tile[r][c4 + 2] = v.z; tile[r][c4 + 3] = v.w;
  }
  __syncthreads();
#pragma unroll
  for (int it = 0; it < 4; ++it) {
    int qd = it * 256 + tid;
    int c = qd >> 4, rq = (qd & 15) * 4;
    ushort4 o;
    o.x = f2bf(tile[rq][c]);     o.y = f2bf(tile[rq + 1][c]);
    o.z = f2bf(tile[rq + 2][c]); o.w = f2bf(tile[rq + 3][c]);
    *(ushort4*)(d + (size_t)(c0 + c) * R + r0 + rq) = o;
  }
}

// ---------------- generic transpose (for w_down) ----------------
__global__ __launch_bounds__(256) void transpose_kernel(
    const float* __restrict__ src, unsigned short* __restrict__ dst, int R, int C) {
  __shared__ float tile[64][65];
  int m = blockIdx.z;
  int r0 = blockIdx.y * 64, c0 = blockIdx.x * 64;
  const float* s = src + (size_t)m * R * C;
  unsigned short* d = dst + (size_t)m * R * C;
  int tid = threadIdx.x;
#pragma unroll
  for (int it = 0; it < 4; ++it) {
    int id4 = it * 256 + tid;
    int r = id4 >> 4, c4 = (id4 & 15) * 4;
    float4 v = *(const float4*)(s + (size_t)(r0 + r) * C + c0 + c4);
    tile[r][c4] = v.x; tile[r][c4 + 1] = v.y; tile[r][c4 + 2] = v.z; tile[r][c4 + 3] = v.w;
  }
  __syncthreads();
#pragma unroll
  for (int it = 0; it < 4; ++it) {
    int qd = it * 256 + tid;
    int c = qd >> 4, rq = (qd & 15) * 4;
    ushort4 o;
    o.x = f2bf(tile[rq][c]);     o.y = f2bf(tile[rq + 1][c]);
    o.z = f2bf(tile[rq + 2][c]); o.w = f2bf(tile[rq + 3][c]);
    *(ushort4*)(d + (size_t)(c0 + c) * R + r0 + rq) = o;
  }
}

// ---------------- gate+up fused grouped GEMM + silu*mul -> h (bf16) ----------------
// R2-exact structure. LDS linear [128][64] bf16; physical (row,c16) holds logical
// (row, c16^(row&7)); staged via GLD16 with pre-swizzled global source col.
__global__ __launch_bounds__(256) void gateup_kernel(
    const unsigned short* __restrict__ xb,
    const unsigned short* __restrict__ wgT,   // [E][I][H] bf16
    const unsigned short* __restrict__ wuT,
    const int* __restrict__ cnt, const int* __restrict__ offs,
    const int* __restrict__ tokL,
    unsigned short* __restrict__ hbuf) {
  int e = blockIdx.z;
  int cnt_e = cnt[e];
  int m0 = blockIdx.y * 128;
  if (m0 >= cnt_e) return;
  int n0 = blockIdx.x * 128;
  int rcnt = cnt_e - m0; if (rcnt > 128) rcnt = 128;

  __shared__ unsigned short As[128 * 64], Gs[128 * 64], Us[128 * 64];  // 48 KB
  __shared__ int trow[128];
  int tid = threadIdx.x;
  if (tid < 128) trow[tid] = tokL[e * CAP + m0 + ((tid < rcnt) ? tid : 0)];
  __syncthreads();

  int lane = tid & 63, wid = tid >> 6;
  int lr = lane >> 3;
  int csrc = ((lane & 7) ^ lr) * 8;          // pre-swizzled source col (shorts)

  const unsigned short* baseA[4];
  const unsigned short* baseG[4];
  const unsigned short* baseU[4];
  int ldso[4];
#pragma unroll
  for (int i = 0; i < 4; ++i) {
    int chunk = i * 4 + wid;
    int row = chunk * 8 + lr;
    baseA[i] = xb + (size_t)trow[row] * H_DIM + csrc;
    size_t wrow = ((size_t)e * I_DIM + n0 + row) * H_DIM + csrc;
    baseG[i] = wgT + wrow;
    baseU[i] = wuT + wrow;
    ldso[i] = chunk * 512;
  }

  int wr = wid >> 1, wc = wid & 1;
  int fr = lane & 15, fg = lane >> 4;
  int fsw = fr & 7;

  f32x4 accg[4][4], accu[4][4];
#pragma unroll
  for (int m = 0; m < 4; ++m)
#pragma unroll
    for (int n = 0; n < 4; ++n) { accg[m][n] = (f32x4)0.f; accu[m][n] = (f32x4)0.f; }

  for (int ks = 0; ks < H_DIM / 64; ++ks) {
    int k0 = ks * 64;
#pragma unroll
    for (int i = 0; i < 4; ++i) {
      GLD16(baseA[i] + k0, As + ldso[i]);
      GLD16(baseG[i] + k0, Gs + ldso[i]);
      GLD16(baseU[i] + k0, Us + ldso[i]);
    }
    __syncthreads();
#pragma unroll
    for (int kk = 0; kk < 2; ++kk) {
      int cb = ((kk * 4 + fg) ^ fsw) * 8;
      bf16x8 am[4], bg[4], bu[4];
#pragma unroll
      for (int m = 0; m < 4; ++m)
        am[m] = *(const bf16x8*)(As + (wr * 64 + m * 16 + fr) * 64 + cb);
#pragma unroll
      for (int n = 0; n < 4; ++n) {
        bg[n] = *(const bf16x8*)(Gs + (wc * 64 + n * 16 + fr) * 64 + cb);
        bu[n] = *(const bf16x8*)(Us + (wc * 64 + n * 16 + fr) * 64 + cb);
      }
#pragma unroll
      for (int m = 0; m < 4; ++m)
#pragma unroll
        for (int n = 0; n < 4; ++n) {
          MFMA16x16x32(accg[m][n], am[m], bg[n]);
          MFMA16x16x32(accu[m][n], am[m], bu[n]);
        }
    }
    __syncthreads();
  }
  int hb = offs[e];
#pragma unroll
  for (int m = 0; m < 4; ++m)
#pragma unroll
    for (int q = 0; q < 4; ++q) {
      int row = wr * 64 + m * 16 + fg * 4 + q;
      if (row < rcnt) {
        size_t rbase = (size_t)(hb + m0 + row) * I_DIM + n0 + wc * 64;
#pragma unroll
        for (int n = 0; n < 4; ++n) {
          float g = accg[m][n][q], u = accu[m][n][q];
          hbuf[rbase + n * 16 + fr] = f2bf(g / (1.f + expf(-g)) * u);
        }
      }
    }
}

// ---------------- down grouped GEMM -> y[slot] (bf16, plain stores) ----------------
__global__ __launch_bounds__(256) void down_kernel(
    const unsigned short* __restrict__ hbuf,
    const unsigned short* __restrict__ wdT,   // [E][H][I] bf16
    const int* __restrict__ cnt, const int* __restrict__ offs,
    unsigned short* __restrict__ y) {         // [16384][H] bf16 compact rows
  int e = blockIdx.z;
  int cnt_e = cnt[e];
  int m0 = blockIdx.y * 128;
  if (m0 >= cnt_e) return;
  int n0 = blockIdx.x * 128;
  int rcnt = cnt_e - m0; if (rcnt > 128) rcnt = 128;
  int hb = offs[e];

  __shared__ unsigned short As[128 * 64], Bs[128 * 64];   // 32 KB
  int tid = threadIdx.x, lane = tid & 63, wid = tid >> 6;
  int lr = lane >> 3;
  int csrc = ((lane & 7) ^ lr) * 8;

  const unsigned short* baseA[4];
  const unsigned short* baseB[4];
  int ldso[4];
#pragma unroll
  for (int i = 0; i < 4; ++i) {
    int chunk = i * 4 + wid;
    int row = chunk * 8 + lr;
    int rowc = (row < rcnt) ? row : (rcnt - 1);           // clamp: stay in-expert
    baseA[i] = hbuf + (size_t)(hb + m0 + rowc) * I_DIM + csrc;
    baseB[i] = wdT + ((size_t)e * H_DIM + n0 + row) * I_DIM + csrc;
    ldso[i] = chunk * 512;
  }

  int wr = wid >> 1, wc = wid & 1, fr = lane & 15, fg = lane >> 4;
  int fsw = fr & 7;

  f32x4 acc[4][4];
#pragma unroll
  for (int m = 0; m < 4; ++m)
#pragma unroll
    for (int n = 0; n < 4; ++n) acc[m][n] = (f32x4)0.f;

  for (int ks = 0; ks < I_DIM / 64; ++ks) {   // 44 steps
    int k0 = ks * 64;
#pragma unroll
    for (int i = 0; i < 4; ++i) {
      GLD16(baseA[i] + k0, As + ldso[i]);
      GLD16(baseB[i] + k0, Bs + ldso[i]);
    }
    __syncthreads();
#pragma unroll
    for (int kk = 0; kk < 2; ++kk) {
      int cb = ((kk * 4 + fg) ^ fsw) * 8;
      bf16x8 am[4], bn[4];
#pragma unroll
      for (int m = 0; m < 4; ++m)
        am[m] = *(const bf16x8*)(As + (wr * 64 + m * 16 + fr) * 64 + cb);
#pragma unroll
      for (int n = 0; n < 4; ++n)
        bn[n] = *(const bf16x8*)(Bs + (wc * 64 + n * 16 + fr) * 64 + cb);
#pragma unroll
      for (int m = 0; m < 4; ++m)
#pragma unroll
        for (int n = 0; n < 4; ++n)
          MFMA16x16x32(acc[m][n], am[m], bn[n]);
    }
    __syncthreads();
  }
#pragma unroll
  for (int m = 0; m < 4; ++m)
#pragma unroll
    for (int q = 0; q < 4; ++q) {
      int row = wr * 64 + m * 16 + fg * 4 + q;
      if (row < rcnt) {
        size_t ybase = (size_t)(hb + m0 + row) * H_DIM + n0 + wc * 64;
#pragma unroll
        for (int n = 0; n < 4; ++n)
          y[ybase + n * 16 + fr] = f2bf(acc[m][n][q]);
      }
    }
}

// ---------------- gather-combine: out[t] = w1*y[c1] + w2*y[c2] ----------------
__global__ __launch_bounds__(256) void combine_kernel(
    const unsigned short* __restrict__ y, const int* __restrict__ offs,
    const int* __restrict__ sA, const int* __restrict__ sB,
    const float* __restrict__ wA, const float* __restrict__ wB,
    float* __restrict__ out) {
  int t = blockIdx.x;
  int s1 = sA[t], s2 = sB[t];
  float w1 = wA[t], w2 = wB[t];
  int c1 = offs[s1 >> 13] + (s1 & (CAP - 1));
  int c2 = offs[s2 >> 13] + (s2 & (CAP - 1));
  int h = threadIdx.x * 4;
  ushort4 a = *(const ushort4*)(y + (size_t)c1 * H_DIM + h);
  ushort4 b = *(const ushort4*)(y + (size_t)c2 * H_DIM + h);
  float4 o;
  o.x = w1 * bf2f(a.x) + w2 * bf2f(b.x);
  o.y = w1 * bf2f(a.y) + w2 * bf2f(b.y);
  o.z = w1 * bf2f(a.z) + w2 * bf2f(b.z);
  o.w = w1 * bf2f(a.w) + w2 * bf2f(b.w);
  *(float4*)(out + (size_t)t * H_DIM + h) = o;
}

extern "C" void kernel_launch(void* const* d_in, const int* in_sizes, int n_in,
                              void* d_out, int out_size, void* d_ws, size_t ws_size,
                              hipStream_t stream) {
  const float* x   = (const float*)d_in[0];
  const float* wr  = (const float*)d_in[1];
  const float* wg  = (const float*)d_in[2];
  const float* wu  = (const float*)d_in[3];
  const float* wd  = (const float*)d_in[4];
  float* out = (float*)d_out;

  char* ws = (char*)d_ws;
  int*   cnt  = (int*)ws;                                   // 32 B
  int*   offs = (int*)(ws + 64);
  int*   tokL = (int*)(ws + 1024);                          // 256 KB
  int*   sA   = (int*)(ws + 1024 + 262144);                 // 32 KB
  int*   sB   = (int*)(ws + 1024 + 262144 + 32768);
  float* wA   = (float*)(ws + 1024 + 262144 + 65536);
  float* wB   = (float*)(ws + 1024 + 262144 + 98304);
  unsigned short* xb  = (unsigned short*)(ws + (1u << 20));
  unsigned short* wgT = (unsigned short*)(ws + (1u << 20) + (size_t)T_TOK * H_DIM * 2);
  unsigned short* wuT = wgT + (size_t)NEXP * I_DIM * H_DIM;
  unsigned short* wdT = wuT + (size_t)NEXP * I_DIM * H_DIM;
  unsigned short* hbuf = wdT + (size_t)NEXP * H_DIM * I_DIM;
  unsigned short* y    = hbuf + (size_t)2 * T_TOK * I_DIM;

  hipMemsetAsync(ws, 0, 64, stream);                        // counts

  router_kernel<<<T_TOK / 32, 256, 0, stream>>>(x, wr, cnt, tokL, sA, sB, wA, wB, xb);
  scan_kernel<<<1, 64, 0, stream>>>(cnt, offs);

  transposeGU_kernel<<<dim3(I_DIM / 64, H_DIM / 64, 16), 256, 0, stream>>>(wg, wu, wgT, wuT);
  transpose_kernel<<<dim3(H_DIM / 64, I_DIM / 64, NEXP), 256, 0, stream>>>(wd, wdT, I_DIM, H_DIM);

  gateup_kernel<<<dim3(I_DIM / 128, CAP / 128, NEXP), 256, 0, stream>>>(
      xb, wgT, wuT, cnt, offs, tokL, hbuf);
  down_kernel<<<dim3(H_DIM / 128, CAP / 128, NEXP), 256, 0, stream>>>(
      hbuf, wdT, cnt, offs, y);
  combine_kernel<<<T_TOK, 256, 0, stream>>>(y, offs, sA, sB, wA, wB, out);
}

// Round 13
// 514.032 us; speedup vs baseline: 1.3633x; 1.0145x over previous
//
#include <hip/hip_runtime.h>

// MoE top-2, E=8, T=8192, H=1024, I=2816. bf16 MFMA grouped-GEMM pipeline.
// R13: consolidation. Single merged transpose kernel (wg+wu+wd, 16B writes,
//      embedded scan) replaces 2 transpose launches + scan launch.
//      Router (LDS-aggregated), gateup (R2-exact), down->y, combine: R12-exact.

#define T_TOK 8192
#define H_DIM 1024
#define I_DIM 2816
#define NEXP  8
#define CAP   8192

typedef short bf16x8 __attribute__((ext_vector_type(8)));
typedef float f32x4  __attribute__((ext_vector_type(4)));

static __device__ __forceinline__ unsigned short f2bf(float f) {
  unsigned u = __float_as_uint(f);
  u = u + 0x7fffu + ((u >> 16) & 1u);   // RNE
  return (unsigned short)(u >> 16);
}
static __device__ __forceinline__ float bf2f(unsigned short u) {
  unsigned v = ((unsigned)u) << 16;
  return __uint_as_float(v);
}

#define MFMA16x16x32(acc, a, b) \
  asm("v_mfma_f32_16x16x32_bf16 %0, %1, %2, %0" : "+v"(acc) : "v"(a), "v"(b))

#define GLD16(g, l) \
  __builtin_amdgcn_global_load_lds((const __attribute__((address_space(1))) void*)(g), \
                                   (__attribute__((address_space(3))) void*)(l), 16, 0, 0)

// ---------------- router: 256 blocks x 32 tokens, LDS-aggregated counts ----------------
__global__ __launch_bounds__(256) void router_kernel(
    const float* __restrict__ x, const float* __restrict__ wr,
    int* __restrict__ cnt, int* __restrict__ tokL,
    int* __restrict__ sA, int* __restrict__ sB,
    float* __restrict__ wA, float* __restrict__ wB,
    unsigned short* __restrict__ xb) {
  __shared__ float rw[NEXP * H_DIM];    // 32 KB
  __shared__ int   selE[64];            // 32 tokens x 2
  __shared__ float selW[64];
  __shared__ int   rankL[64];
  __shared__ int   baseL[NEXP];
  int tid = threadIdx.x;
#pragma unroll
  for (int it = 0; it < 8; ++it) {
    int i4 = it * 256 + tid;
    ((float4*)rw)[i4] = ((const float4*)wr)[i4];
  }
  __syncthreads();
  int wid = tid >> 6, lane = tid & 63;
  int tbase = blockIdx.x * 32;

  for (int it = 0; it < 8; ++it) {      // 8 tokens per wave
    int tl = wid * 8 + it;              // local token 0..31
    int t = tbase + tl;
    float a[NEXP];
#pragma unroll
    for (int e = 0; e < NEXP; ++e) a[e] = 0.f;
#pragma unroll
    for (int hc = 0; hc < 4; ++hc) {
      int h = hc * 256 + lane * 4;
      float4 xv = *(const float4*)(x + (size_t)t * H_DIM + h);
      ushort4 o;
      o.x = f2bf(xv.x); o.y = f2bf(xv.y); o.z = f2bf(xv.z); o.w = f2bf(xv.w);
      *(ushort4*)(xb + (size_t)t * H_DIM + h) = o;
#pragma unroll
      for (int e = 0; e < NEXP; ++e) {
        float4 w4 = *(const float4*)(&rw[e * H_DIM + h]);
        a[e] += xv.x * w4.x + xv.y * w4.y + xv.z * w4.z + xv.w * w4.w;
      }
    }
#pragma unroll
    for (int e = 0; e < NEXP; ++e) {
      float v = a[e];
      for (int off = 32; off > 0; off >>= 1) v += __shfl_xor(v, off, 64);
      a[e] = v;
    }
    if (lane == 0) {
      int e1 = 0; float l1 = a[0];
#pragma unroll
      for (int e = 1; e < NEXP; ++e) if (a[e] > l1) { l1 = a[e]; e1 = e; }
      int e2 = -1; float l2 = -3.4e38f;
#pragma unroll
      for (int e = 0; e < NEXP; ++e) if (e != e1 && a[e] > l2) { l2 = a[e]; e2 = e; }
      float q = expf(l2 - l1);
      float w1 = 1.f / (1.f + q);
      selE[tl * 2]     = e1; selW[tl * 2]     = w1;
      selE[tl * 2 + 1] = e2; selW[tl * 2 + 1] = q * w1;
    }
  }
  __syncthreads();
  if (tid == 0) {                       // serial local count+rank (64 entries)
    int cl[NEXP];
#pragma unroll
    for (int e = 0; e < NEXP; ++e) cl[e] = 0;
    for (int i = 0; i < 64; ++i) rankL[i] = cl[selE[i]]++;
    for (int e = 0; e < NEXP; ++e)
      baseL[e] = cl[e] ? atomicAdd(&cnt[e], cl[e]) : 0;
  }
  __syncthreads();
  if (tid < 64) {                       // scatter
    int e = selE[tid];
    int p = baseL[e] + rankL[tid];
    int t = tbase + (tid >> 1);
    tokL[e * CAP + p] = t;
    int slot = e * CAP + p;
    if (tid & 1) { sB[t] = slot; wB[t] = selW[tid]; }
    else         { sA[t] = slot; wA[t] = selW[tid]; }
  }
}

// ---------------- merged transpose+cast: wg,wu: [8][1024][2816] -> [8][2816][1024];
//                  wd: [8][2816][1024] -> [8][1024][2816]. 16B writes. Embedded scan. ----
__global__ __launch_bounds__(256) void transposeAll_kernel(
    const float* __restrict__ wg, const float* __restrict__ wu,
    const float* __restrict__ wd,
    unsigned short* __restrict__ wgT, unsigned short* __restrict__ wuT,
    unsigned short* __restrict__ wdT,
    const int* __restrict__ cnt, int* __restrict__ offs) {
  // embedded scan (router completed via stream order; gateup launches after us)
  if (blockIdx.z == 23 && blockIdx.x == 0 && threadIdx.x == 0) {
    int s = 0;
    for (int e = 0; e < NEXP; ++e) { offs[e] = s; s += cnt[e]; }
  }
  __shared__ float tile[64][65];
  int z = blockIdx.z;
  const float* src; unsigned short* dst; int R, C;
  if (z < 8)       { src = wg; dst = wgT; R = H_DIM; C = I_DIM; }
  else if (z < 16) { src = wu; dst = wuT; R = H_DIM; C = I_DIM; }
  else             { src = wd; dst = wdT; R = I_DIM; C = H_DIM; }
  int m = z & 7;
  int nC = C >> 6;
  int tx = blockIdx.x % nC, ty = blockIdx.x / nC;
  int r0 = ty * 64, c0 = tx * 64;
  const float* s = src + (size_t)m * R * C;
  unsigned short* d = dst + (size_t)m * R * C;
  int tid = threadIdx.x;
#pragma unroll
  for (int it = 0; it < 4; ++it) {
    int id4 = it * 256 + tid;
    int r = id4 >> 4, c4 = (id4 & 15) * 4;
    float4 v = *(const float4*)(s + (size_t)(r0 + r) * C + c0 + c4);
    tile[r][c4] = v.x; tile[r][c4 + 1] = v.y; tile[r][c4 + 2] = v.z; tile[r][c4 + 3] = v.w;
  }
  __syncthreads();
#pragma unroll
  for (int it = 0; it < 2; ++it) {
    int qd = it * 256 + tid;
    int c = qd >> 3, rq = (qd & 7) * 8;
    unsigned short v0 = f2bf(tile[rq][c]),     v1 = f2bf(tile[rq + 1][c]);
    unsigned short v2 = f2bf(tile[rq + 2][c]), v3 = f2bf(tile[rq + 3][c]);
    unsigned short v4 = f2bf(tile[rq + 4][c]), v5 = f2bf(tile[rq + 5][c]);
    unsigned short v6 = f2bf(tile[rq + 6][c]), v7 = f2bf(tile[rq + 7][c]);
    uint4 o;
    o.x = v0 | ((unsigned)v1 << 16);
    o.y = v2 | ((unsigned)v3 << 16);
    o.z = v4 | ((unsigned)v5 << 16);
    o.w = v6 | ((unsigned)v7 << 16);
    *(uint4*)(d + (size_t)(c0 + c) * R + r0 + rq) = o;
  }
}

// ---------------- gate+up fused grouped GEMM + silu*mul -> h (bf16) ----------------
// R2-exact structure. LDS linear [128][64] bf16; physical (row,c16) holds logical
// (row, c16^(row&7)); staged via GLD16 with pre-swizzled global source col.
__global__ __launch_bounds__(256) void gateup_kernel(
    const unsigned short* __restrict__ xb,
    const unsigned short* __restrict__ wgT,   // [E][I][H] bf16
    const unsigned short* __restrict__ wuT,
    const int* __restrict__ cnt, const int* __restrict__ offs,
    const int* __restrict__ tokL,
    unsigned short* __restrict__ hbuf) {
  int e = blockIdx.z;
  int cnt_e = cnt[e];
  int m0 = blockIdx.y * 128;
  if (m0 >= cnt_e) return;
  int n0 = blockIdx.x * 128;
  int rcnt = cnt_e - m0; if (rcnt > 128) rcnt = 128;

  __shared__ unsigned short As[128 * 64], Gs[128 * 64], Us[128 * 64];  // 48 KB
  __shared__ int trow[128];
  int tid = threadIdx.x;
  if (tid < 128) trow[tid] = tokL[e * CAP + m0 + ((tid < rcnt) ? tid : 0)];
  __syncthreads();

  int lane = tid & 63, wid = tid >> 6;
  int lr = lane >> 3;
  int csrc = ((lane & 7) ^ lr) * 8;          // pre-swizzled source col (shorts)

  const unsigned short* baseA[4];
  const unsigned short* baseG[4];
  const unsigned short* baseU[4];
  int ldso[4];
#pragma unroll
  for (int i = 0; i < 4; ++i) {
    int chunk = i * 4 + wid;
    int row = chunk * 8 + lr;
    baseA[i] = xb + (size_t)trow[row] * H_DIM + csrc;
    size_t wrow = ((size_t)e * I_DIM + n0 + row) * H_DIM + csrc;
    baseG[i] = wgT + wrow;
    baseU[i] = wuT + wrow;
    ldso[i] = chunk * 512;
  }

  int wr = wid >> 1, wc = wid & 1;
  int fr = lane & 15, fg = lane >> 4;
  int fsw = fr & 7;

  f32x4 accg[4][4], accu[4][4];
#pragma unroll
  for (int m = 0; m < 4; ++m)
#pragma unroll
    for (int n = 0; n < 4; ++n) { accg[m][n] = (f32x4)0.f; accu[m][n] = (f32x4)0.f; }

  for (int ks = 0; ks < H_DIM / 64; ++ks) {
    int k0 = ks * 64;
#pragma unroll
    for (int i = 0; i < 4; ++i) {
      GLD16(baseA[i] + k0, As + ldso[i]);
      GLD16(baseG[i] + k0, Gs + ldso[i]);
      GLD16(baseU[i] + k0, Us + ldso[i]);
    }
    __syncthreads();
#pragma unroll
    for (int kk = 0; kk < 2; ++kk) {
      int cb = ((kk * 4 + fg) ^ fsw) * 8;
      bf16x8 am[4], bg[4], bu[4];
#pragma unroll
      for (int m = 0; m < 4; ++m)
        am[m] = *(const bf16x8*)(As + (wr * 64 + m * 16 + fr) * 64 + cb);
#pragma unroll
      for (int n = 0; n < 4; ++n) {
        bg[n] = *(const bf16x8*)(Gs + (wc * 64 + n * 16 + fr) * 64 + cb);
        bu[n] = *(const bf16x8*)(Us + (wc * 64 + n * 16 + fr) * 64 + cb);
      }
#pragma unroll
      for (int m = 0; m < 4; ++m)
#pragma unroll
        for (int n = 0; n < 4; ++n) {
          MFMA16x16x32(accg[m][n], am[m], bg[n]);
          MFMA16x16x32(accu[m][n], am[m], bu[n]);
        }
    }
    __syncthreads();
  }
  int hb = offs[e];
#pragma unroll
  for (int m = 0; m < 4; ++m)
#pragma unroll
    for (int q = 0; q < 4; ++q) {
      int row = wr * 64 + m * 16 + fg * 4 + q;
      if (row < rcnt) {
        size_t rbase = (size_t)(hb + m0 + row) * I_DIM + n0 + wc * 64;
#pragma unroll
        for (int n = 0; n < 4; ++n) {
          float g = accg[m][n][q], u = accu[m][n][q];
          hbuf[rbase + n * 16 + fr] = f2bf(g / (1.f + expf(-g)) * u);
        }
      }
    }
}

// ---------------- down grouped GEMM -> y[slot] (bf16, plain stores) ----------------
__global__ __launch_bounds__(256) void down_kernel(
    const unsigned short* __restrict__ hbuf,
    const unsigned short* __restrict__ wdT,   // [E][H][I] bf16
    const int* __restrict__ cnt, const int* __restrict__ offs,
    unsigned short* __restrict__ y) {         // [16384][H] bf16 compact rows
  int e = blockIdx.z;
  int cnt_e = cnt[e];
  int m0 = blockIdx.y * 128;
  if (m0 >= cnt_e) return;
  int n0 = blockIdx.x * 128;
  int rcnt = cnt_e - m0; if (rcnt > 128) rcnt = 128;
  int hb = offs[e];

  __shared__ unsigned short As[128 * 64], Bs[128 * 64];   // 32 KB
  int tid = threadIdx.x, lane = tid & 63, wid = tid >> 6;
  int lr = lane >> 3;
  int csrc = ((lane & 7) ^ lr) * 8;

  const unsigned short* baseA[4];
  const unsigned short* baseB[4];
  int ldso[4];
#pragma unroll
  for (int i = 0; i < 4; ++i) {
    int chunk = i * 4 + wid;
    int row = chunk * 8 + lr;
    int rowc = (row < rcnt) ? row : (rcnt - 1);           // clamp: stay in-expert
    baseA[i] = hbuf + (size_t)(hb + m0 + rowc) * I_DIM + csrc;
    baseB[i] = wdT + ((size_t)e * H_DIM + n0 + row) * I_DIM + csrc;
    ldso[i] = chunk * 512;
  }

  int wr = wid >> 1, wc = wid & 1, fr = lane & 15, fg = lane >> 4;
  int fsw = fr & 7;

  f32x4 acc[4][4];
#pragma unroll
  for (int m = 0; m < 4; ++m)
#pragma unroll
    for (int n = 0; n < 4; ++n) acc[m][n] = (f32x4)0.f;

  for (int ks = 0; ks < I_DIM / 64; ++ks) {   // 44 steps
    int k0 = ks * 64;
#pragma unroll
    for (int i = 0; i < 4; ++i) {
      GLD16(baseA[i] + k0, As + ldso[i]);
      GLD16(baseB[i] + k0, Bs + ldso[i]);
    }
    __syncthreads();
#pragma unroll
    for (int kk = 0; kk < 2; ++kk) {
      int cb = ((kk * 4 + fg) ^ fsw) * 8;
      bf16x8 am[4], bn[4];
#pragma unroll
      for (int m = 0; m < 4; ++m)
        am[m] = *(const bf16x8*)(As + (wr * 64 + m * 16 + fr) * 64 + cb);
#pragma unroll
      for (int n = 0; n < 4; ++n)
        bn[n] = *(const bf16x8*)(Bs + (wc * 64 + n * 16 + fr) * 64 + cb);
#pragma unroll
      for (int m = 0; m < 4; ++m)
#pragma unroll
        for (int n = 0; n < 4; ++n)
          MFMA16x16x32(acc[m][n], am[m], bn[n]);
    }
    __syncthreads();
  }
#pragma unroll
  for (int m = 0; m < 4; ++m)
#pragma unroll
    for (int q = 0; q < 4; ++q) {
      int row = wr * 64 + m * 16 + fg * 4 + q;
      if (row < rcnt) {
        size_t ybase = (size_t)(hb + m0 + row) * H_DIM + n0 + wc * 64;
#pragma unroll
        for (int n = 0; n < 4; ++n)
          y[ybase + n * 16 + fr] = f2bf(acc[m][n][q]);
      }
    }
}

// ---------------- gather-combine: out[t] = w1*y[c1] + w2*y[c2] ----------------
__global__ __launch_bounds__(256) void combine_kernel(
    const unsigned short* __restrict__ y, const int* __restrict__ offs,
    const int* __restrict__ sA, const int* __restrict__ sB,
    const float* __restrict__ wA, const float* __restrict__ wB,
    float* __restrict__ out) {
  int t = blockIdx.x;
  int s1 = sA[t], s2 = sB[t];
  float w1 = wA[t], w2 = wB[t];
  int c1 = offs[s1 >> 13] + (s1 & (CAP - 1));
  int c2 = offs[s2 >> 13] + (s2 & (CAP - 1));
  int h = threadIdx.x * 4;
  ushort4 a = *(const ushort4*)(y + (size_t)c1 * H_DIM + h);
  ushort4 b = *(const ushort4*)(y + (size_t)c2 * H_DIM + h);
  float4 o;
  o.x = w1 * bf2f(a.x) + w2 * bf2f(b.x);
  o.y = w1 * bf2f(a.y) + w2 * bf2f(b.y);
  o.z = w1 * bf2f(a.z) + w2 * bf2f(b.z);
  o.w = w1 * bf2f(a.w) + w2 * bf2f(b.w);
  *(float4*)(out + (size_t)t * H_DIM + h) = o;
}

extern "C" void kernel_launch(void* const* d_in, const int* in_sizes, int n_in,
                              void* d_out, int out_size, void* d_ws, size_t ws_size,
                              hipStream_t stream) {
  const float* x   = (const float*)d_in[0];
  const float* wr  = (const float*)d_in[1];
  const float* wg  = (const float*)d_in[2];
  const float* wu  = (const float*)d_in[3];
  const float* wd  = (const float*)d_in[4];
  float* out = (float*)d_out;

  char* ws = (char*)d_ws;
  int*   cnt  = (int*)ws;                                   // 32 B
  int*   offs = (int*)(ws + 64);
  int*   tokL = (int*)(ws + 1024);                          // 256 KB
  int*   sA   = (int*)(ws + 1024 + 262144);                 // 32 KB
  int*   sB   = (int*)(ws + 1024 + 262144 + 32768);
  float* wA   = (float*)(ws + 1024 + 262144 + 65536);
  float* wB   = (float*)(ws + 1024 + 262144 + 98304);
  unsigned short* xb  = (unsigned short*)(ws + (1u << 20));
  unsigned short* wgT = (unsigned short*)(ws + (1u << 20) + (size_t)T_TOK * H_DIM * 2);
  unsigned short* wuT = wgT + (size_t)NEXP * I_DIM * H_DIM;
  unsigned short* wdT = wuT + (size_t)NEXP * I_DIM * H_DIM;
  unsigned short* hbuf = wdT + (size_t)NEXP * H_DIM * I_DIM;
  unsigned short* y    = hbuf + (size_t)2 * T_TOK * I_DIM;

  hipMemsetAsync(ws, 0, 64, stream);                        // counts

  router_kernel<<<T_TOK / 32, 256, 0, stream>>>(x, wr, cnt, tokL, sA, sB, wA, wB, xb);
  transposeAll_kernel<<<dim3(704, 1, 24), 256, 0, stream>>>(
      wg, wu, wd, wgT, wuT, wdT, cnt, offs);
  gateup_kernel<<<dim3(I_DIM / 128, CAP / 128, NEXP), 256, 0, stream>>>(
      xb, wgT, wuT, cnt, offs, tokL, hbuf);
  down_kernel<<<dim3(H_DIM / 128, CAP / 128, NEXP), 256, 0, stream>>>(
      hbuf, wdT, cnt, offs, y);
  combine_kernel<<<T_TOK, 256, 0, stream>>>(y, offs, sA, sB, wA, wB, out);
}

// Round 14
// 499.721 us; speedup vs baseline: 1.4024x; 1.0286x over previous
//
#include <hip/hip_runtime.h>

// MoE top-2, E=8, T=8192, H=1024, I=2816. bf16 MFMA grouped-GEMM pipeline.
// R14: router merged into transposeAll as z-slice 24 (concurrent with weight
//      transposes; router's ~15us hidden under HBM-bound transpose). LDS
//      manually unioned (33.6KB). Scan back to its own tiny launch (race-free).
//      Gateup/down/combine: R13-exact.

#define T_TOK 8192
#define H_DIM 1024
#define I_DIM 2816
#define NEXP  8
#define CAP   8192

typedef short bf16x8 __attribute__((ext_vector_type(8)));
typedef float f32x4  __attribute__((ext_vector_type(4)));

static __device__ __forceinline__ unsigned short f2bf(float f) {
  unsigned u = __float_as_uint(f);
  u = u + 0x7fffu + ((u >> 16) & 1u);   // RNE
  return (unsigned short)(u >> 16);
}
static __device__ __forceinline__ float bf2f(unsigned short u) {
  unsigned v = ((unsigned)u) << 16;
  return __uint_as_float(v);
}

#define MFMA16x16x32(acc, a, b) \
  asm("v_mfma_f32_16x16x32_bf16 %0, %1, %2, %0" : "+v"(acc) : "v"(a), "v"(b))

#define GLD16(g, l) \
  __builtin_amdgcn_global_load_lds((const __attribute__((address_space(1))) void*)(g), \
                                   (__attribute__((address_space(3))) void*)(l), 16, 0, 0)

// ---------------- merged: weight transposes (z<24) + router (z==24) ----------------
// transposes: wg,wu [8][1024][2816] -> [8][2816][1024] bf16; wd [8][2816][1024] -> [8][1024][2816].
// router: 256 blocks x 32 tokens, LDS-aggregated counts (8 atomics/block).
__global__ __launch_bounds__(256) void transposeAll_kernel(
    const float* __restrict__ x, const float* __restrict__ wr,
    const float* __restrict__ wg, const float* __restrict__ wu,
    const float* __restrict__ wd,
    unsigned short* __restrict__ wgT, unsigned short* __restrict__ wuT,
    unsigned short* __restrict__ wdT,
    unsigned short* __restrict__ xb,
    int* __restrict__ cnt, int* __restrict__ tokL,
    int* __restrict__ sA, int* __restrict__ sB,
    float* __restrict__ wA, float* __restrict__ wB) {
  __shared__ char smem[33600];          // union: router 33.1KB | transpose tile 16.7KB
  int z = blockIdx.z;
  int tid = threadIdx.x;

  if (z == 24) {                        // ---- router slice ----
    if (blockIdx.x >= T_TOK / 32) return;
    float* rw   = (float*)smem;                 // 32 KB
    int*   selE = (int*)(smem + 32768);         // 64
    float* selW = (float*)(smem + 33024);       // 64
    int*   rankL= (int*)(smem + 33280);         // 64
    int*   baseL= (int*)(smem + 33536);         // 8
#pragma unroll
    for (int it = 0; it < 8; ++it) {
      int i4 = it * 256 + tid;
      ((float4*)rw)[i4] = ((const float4*)wr)[i4];
    }
    __syncthreads();
    int wid = tid >> 6, lane = tid & 63;
    int tbase = blockIdx.x * 32;
    for (int it = 0; it < 8; ++it) {    // 8 tokens per wave
      int tl = wid * 8 + it;
      int t = tbase + tl;
      float a[NEXP];
#pragma unroll
      for (int e = 0; e < NEXP; ++e) a[e] = 0.f;
#pragma unroll
      for (int hc = 0; hc < 4; ++hc) {
        int h = hc * 256 + lane * 4;
        float4 xv = *(const float4*)(x + (size_t)t * H_DIM + h);
        ushort4 o;
        o.x = f2bf(xv.x); o.y = f2bf(xv.y); o.z = f2bf(xv.z); o.w = f2bf(xv.w);
        *(ushort4*)(xb + (size_t)t * H_DIM + h) = o;
#pragma unroll
        for (int e = 0; e < NEXP; ++e) {
          float4 w4 = *(const float4*)(&rw[e * H_DIM + h]);
          a[e] += xv.x * w4.x + xv.y * w4.y + xv.z * w4.z + xv.w * w4.w;
        }
      }
#pragma unroll
      for (int e = 0; e < NEXP; ++e) {
        float v = a[e];
        for (int off = 32; off > 0; off >>= 1) v += __shfl_xor(v, off, 64);
        a[e] = v;
      }
      if (lane == 0) {
        int e1 = 0; float l1 = a[0];
#pragma unroll
        for (int e = 1; e < NEXP; ++e) if (a[e] > l1) { l1 = a[e]; e1 = e; }
        int e2 = -1; float l2 = -3.4e38f;
#pragma unroll
        for (int e = 0; e < NEXP; ++e) if (e != e1 && a[e] > l2) { l2 = a[e]; e2 = e; }
        float q = expf(l2 - l1);
        float w1 = 1.f / (1.f + q);
        selE[tl * 2]     = e1; selW[tl * 2]     = w1;
        selE[tl * 2 + 1] = e2; selW[tl * 2 + 1] = q * w1;
      }
    }
    __syncthreads();
    if (tid == 0) {                     // serial local count+rank (64 entries)
      int cl[NEXP];
#pragma unroll
      for (int e = 0; e < NEXP; ++e) cl[e] = 0;
      for (int i = 0; i < 64; ++i) rankL[i] = cl[selE[i]]++;
      for (int e = 0; e < NEXP; ++e)
        baseL[e] = cl[e] ? atomicAdd(&cnt[e], cl[e]) : 0;
    }
    __syncthreads();
    if (tid < 64) {                     // scatter
      int e = selE[tid];
      int p = baseL[e] + rankL[tid];
      int t = tbase + (tid >> 1);
      tokL[e * CAP + p] = t;
      int slot = e * CAP + p;
      if (tid & 1) { sB[t] = slot; wB[t] = selW[tid]; }
      else         { sA[t] = slot; wA[t] = selW[tid]; }
    }
    return;
  }

  // ---- transpose slices ----
  float (*tile)[65] = (float(*)[65])smem;       // 64x65 f32 = 16.6 KB
  const float* src; unsigned short* dst; int R, C;
  if (z < 8)       { src = wg; dst = wgT; R = H_DIM; C = I_DIM; }
  else if (z < 16) { src = wu; dst = wuT; R = H_DIM; C = I_DIM; }
  else             { src = wd; dst = wdT; R = I_DIM; C = H_DIM; }
  int m = z & 7;
  int nC = C >> 6;
  int tx = blockIdx.x % nC, ty = blockIdx.x / nC;
  int r0 = ty * 64, c0 = tx * 64;
  const float* s = src + (size_t)m * R * C;
  unsigned short* d = dst + (size_t)m * R * C;
#pragma unroll
  for (int it = 0; it < 4; ++it) {
    int id4 = it * 256 + tid;
    int r = id4 >> 4, c4 = (id4 & 15) * 4;
    float4 v = *(const float4*)(s + (size_t)(r0 + r) * C + c0 + c4);
    tile[r][c4] = v.x; tile[r][c4 + 1] = v.y; tile[r][c4 + 2] = v.z; tile[r][c4 + 3] = v.w;
  }
  __syncthreads();
#pragma unroll
  for (int it = 0; it < 2; ++it) {
    int qd = it * 256 + tid;
    int c = qd >> 3, rq = (qd & 7) * 8;
    unsigned short v0 = f2bf(tile[rq][c]),     v1 = f2bf(tile[rq + 1][c]);
    unsigned short v2 = f2bf(tile[rq + 2][c]), v3 = f2bf(tile[rq + 3][c]);
    unsigned short v4 = f2bf(tile[rq + 4][c]), v5 = f2bf(tile[rq + 5][c]);
    unsigned short v6 = f2bf(tile[rq + 6][c]), v7 = f2bf(tile[rq + 7][c]);
    uint4 o;
    o.x = v0 | ((unsigned)v1 << 16);
    o.y = v2 | ((unsigned)v3 << 16);
    o.z = v4 | ((unsigned)v5 << 16);
    o.w = v6 | ((unsigned)v7 << 16);
    *(uint4*)(d + (size_t)(c0 + c) * R + r0 + rq) = o;
  }
}

__global__ void scan_kernel(const int* __restrict__ cnt, int* __restrict__ offs) {
  if (threadIdx.x == 0) {
    int s = 0;
    for (int e = 0; e < NEXP; ++e) { offs[e] = s; s += cnt[e]; }
  }
}

// ---------------- gate+up fused grouped GEMM + silu*mul -> h (bf16) ----------------
// R2-exact structure. LDS linear [128][64] bf16; physical (row,c16) holds logical
// (row, c16^(row&7)); staged via GLD16 with pre-swizzled global source col.
__global__ __launch_bounds__(256) void gateup_kernel(
    const unsigned short* __restrict__ xb,
    const unsigned short* __restrict__ wgT,   // [E][I][H] bf16
    const unsigned short* __restrict__ wuT,
    const int* __restrict__ cnt, const int* __restrict__ offs,
    const int* __restrict__ tokL,
    unsigned short* __restrict__ hbuf) {
  int e = blockIdx.z;
  int cnt_e = cnt[e];
  int m0 = blockIdx.y * 128;
  if (m0 >= cnt_e) return;
  int n0 = blockIdx.x * 128;
  int rcnt = cnt_e - m0; if (rcnt > 128) rcnt = 128;

  __shared__ unsigned short As[128 * 64], Gs[128 * 64], Us[128 * 64];  // 48 KB
  __shared__ int trow[128];
  int tid = threadIdx.x;
  if (tid < 128) trow[tid] = tokL[e * CAP + m0 + ((tid < rcnt) ? tid : 0)];
  __syncthreads();

  int lane = tid & 63, wid = tid >> 6;
  int lr = lane >> 3;
  int csrc = ((lane & 7) ^ lr) * 8;          // pre-swizzled source col (shorts)

  const unsigned short* baseA[4];
  const unsigned short* baseG[4];
  const unsigned short* baseU[4];
  int ldso[4];
#pragma unroll
  for (int i = 0; i < 4; ++i) {
    int chunk = i * 4 + wid;
    int row = chunk * 8 + lr;
    baseA[i] = xb + (size_t)trow[row] * H_DIM + csrc;
    size_t wrow = ((size_t)e * I_DIM + n0 + row) * H_DIM + csrc;
    baseG[i] = wgT + wrow;
    baseU[i] = wuT + wrow;
    ldso[i] = chunk * 512;
  }

  int wr = wid >> 1, wc = wid & 1;
  int fr = lane & 15, fg = lane >> 4;
  int fsw = fr & 7;

  f32x4 accg[4][4], accu[4][4];
#pragma unroll
  for (int m = 0; m < 4; ++m)
#pragma unroll
    for (int n = 0; n < 4; ++n) { accg[m][n] = (f32x4)0.f; accu[m][n] = (f32x4)0.f; }

  for (int ks = 0; ks < H_DIM / 64; ++ks) {
    int k0 = ks * 64;
#pragma unroll
    for (int i = 0; i < 4; ++i) {
      GLD16(baseA[i] + k0, As + ldso[i]);
      GLD16(baseG[i] + k0, Gs + ldso[i]);
      GLD16(baseU[i] + k0, Us + ldso[i]);
    }
    __syncthreads();
#pragma unroll
    for (int kk = 0; kk < 2; ++kk) {
      int cb = ((kk * 4 + fg) ^ fsw) * 8;
      bf16x8 am[4], bg[4], bu[4];
#pragma unroll
      for (int m = 0; m < 4; ++m)
        am[m] = *(const bf16x8*)(As + (wr * 64 + m * 16 + fr) * 64 + cb);
#pragma unroll
      for (int n = 0; n < 4; ++n) {
        bg[n] = *(const bf16x8*)(Gs + (wc * 64 + n * 16 + fr) * 64 + cb);
        bu[n] = *(const bf16x8*)(Us + (wc * 64 + n * 16 + fr) * 64 + cb);
      }
#pragma unroll
      for (int m = 0; m < 4; ++m)
#pragma unroll
        for (int n = 0; n < 4; ++n) {
          MFMA16x16x32(accg[m][n], am[m], bg[n]);
          MFMA16x16x32(accu[m][n], am[m], bu[n]);
        }
    }
    __syncthreads();
  }
  int hb = offs[e];
#pragma unroll
  for (int m = 0; m < 4; ++m)
#pragma unroll
    for (int q = 0; q < 4; ++q) {
      int row = wr * 64 + m * 16 + fg * 4 + q;
      if (row < rcnt) {
        size_t rbase = (size_t)(hb + m0 + row) * I_DIM + n0 + wc * 64;
#pragma unroll
        for (int n = 0; n < 4; ++n) {
          float g = accg[m][n][q], u = accu[m][n][q];
          hbuf[rbase + n * 16 + fr] = f2bf(g / (1.f + expf(-g)) * u);
        }
      }
    }
}

// ---------------- down grouped GEMM -> y[slot] (bf16, plain stores) ----------------
__global__ __launch_bounds__(256) void down_kernel(
    const unsigned short* __restrict__ hbuf,
    const unsigned short* __restrict__ wdT,   // [E][H][I] bf16
    const int* __restrict__ cnt, const int* __restrict__ offs,
    unsigned short* __restrict__ y) {         // [16384][H] bf16 compact rows
  int e = blockIdx.z;
  int cnt_e = cnt[e];
  int m0 = blockIdx.y * 128;
  if (m0 >= cnt_e) return;
  int n0 = blockIdx.x * 128;
  int rcnt = cnt_e - m0; if (rcnt > 128) rcnt = 128;
  int hb = offs[e];

  __shared__ unsigned short As[128 * 64], Bs[128 * 64];   // 32 KB
  int tid = threadIdx.x, lane = tid & 63, wid = tid >> 6;
  int lr = lane >> 3;
  int csrc = ((lane & 7) ^ lr) * 8;

  const unsigned short* baseA[4];
  const unsigned short* baseB[4];
  int ldso[4];
#pragma unroll
  for (int i = 0; i < 4; ++i) {
    int chunk = i * 4 + wid;
    int row = chunk * 8 + lr;
    int rowc = (row < rcnt) ? row : (rcnt - 1);           // clamp: stay in-expert
    baseA[i] = hbuf + (size_t)(hb + m0 + rowc) * I_DIM + csrc;
    baseB[i] = wdT + ((size_t)e * H_DIM + n0 + row) * I_DIM + csrc;
    ldso[i] = chunk * 512;
  }

  int wr = wid >> 1, wc = wid & 1, fr = lane & 15, fg = lane >> 4;
  int fsw = fr & 7;

  f32x4 acc[4][4];
#pragma unroll
  for (int m = 0; m < 4; ++m)
#pragma unroll
    for (int n = 0; n < 4; ++n) acc[m][n] = (f32x4)0.f;

  for (int ks = 0; ks < I_DIM / 64; ++ks) {   // 44 steps
    int k0 = ks * 64;
#pragma unroll
    for (int i = 0; i < 4; ++i) {
      GLD16(baseA[i] + k0, As + ldso[i]);
      GLD16(baseB[i] + k0, Bs + ldso[i]);
    }
    __syncthreads();
#pragma unroll
    for (int kk = 0; kk < 2; ++kk) {
      int cb = ((kk * 4 + fg) ^ fsw) * 8;
      bf16x8 am[4], bn[4];
#pragma unroll
      for (int m = 0; m < 4; ++m)
        am[m] = *(const bf16x8*)(As + (wr * 64 + m * 16 + fr) * 64 + cb);
#pragma unroll
      for (int n = 0; n < 4; ++n)
        bn[n] = *(const bf16x8*)(Bs + (wc * 64 + n * 16 + fr) * 64 + cb);
#pragma unroll
      for (int m = 0; m < 4; ++m)
#pragma unroll
        for (int n = 0; n < 4; ++n)
          MFMA16x16x32(acc[m][n], am[m], bn[n]);
    }
    __syncthreads();
  }
#pragma unroll
  for (int m = 0; m < 4; ++m)
#pragma unroll
    for (int q = 0; q < 4; ++q) {
      int row = wr * 64 + m * 16 + fg * 4 + q;
      if (row < rcnt) {
        size_t ybase = (size_t)(hb + m0 + row) * H_DIM + n0 + wc * 64;
#pragma unroll
        for (int n = 0; n < 4; ++n)
          y[ybase + n * 16 + fr] = f2bf(acc[m][n][q]);
      }
    }
}

// ---------------- gather-combine: out[t] = w1*y[c1] + w2*y[c2] ----------------
__global__ __launch_bounds__(256) void combine_kernel(
    const unsigned short* __restrict__ y, const int* __restrict__ offs,
    const int* __restrict__ sA, const int* __restrict__ sB,
    const float* __restrict__ wA, const float* __restrict__ wB,
    float* __restrict__ out) {
  int t = blockIdx.x;
  int s1 = sA[t], s2 = sB[t];
  float w1 = wA[t], w2 = wB[t];
  int c1 = offs[s1 >> 13] + (s1 & (CAP - 1));
  int c2 = offs[s2 >> 13] + (s2 & (CAP - 1));
  int h = threadIdx.x * 4;
  ushort4 a = *(const ushort4*)(y + (size_t)c1 * H_DIM + h);
  ushort4 b = *(const ushort4*)(y + (size_t)c2 * H_DIM + h);
  float4 o;
  o.x = w1 * bf2f(a.x) + w2 * bf2f(b.x);
  o.y = w1 * bf2f(a.y) + w2 * bf2f(b.y);
  o.z = w1 * bf2f(a.z) + w2 * bf2f(b.z);
  o.w = w1 * bf2f(a.w) + w2 * bf2f(b.w);
  *(float4*)(out + (size_t)t * H_DIM + h) = o;
}

extern "C" void kernel_launch(void* const* d_in, const int* in_sizes, int n_in,
                              void* d_out, int out_size, void* d_ws, size_t ws_size,
                              hipStream_t stream) {
  const float* x   = (const float*)d_in[0];
  const float* wr  = (const float*)d_in[1];
  const float* wg  = (const float*)d_in[2];
  const float* wu  = (const float*)d_in[3];
  const float* wd  = (const float*)d_in[4];
  float* out = (float*)d_out;

  char* ws = (char*)d_ws;
  int*   cnt  = (int*)ws;                                   // 32 B
  int*   offs = (int*)(ws + 64);
  int*   tokL = (int*)(ws + 1024);                          // 256 KB
  int*   sA   = (int*)(ws + 1024 + 262144);                 // 32 KB
  int*   sB   = (int*)(ws + 1024 + 262144 + 32768);
  float* wA   = (float*)(ws + 1024 + 262144 + 65536);
  float* wB   = (float*)(ws + 1024 + 262144 + 98304);
  unsigned short* xb  = (unsigned short*)(ws + (1u << 20));
  unsigned short* wgT = (unsigned short*)(ws + (1u << 20) + (size_t)T_TOK * H_DIM * 2);
  unsigned short* wuT = wgT + (size_t)NEXP * I_DIM * H_DIM;
  unsigned short* wdT = wuT + (size_t)NEXP * I_DIM * H_DIM;
  unsigned short* hbuf = wdT + (size_t)NEXP * H_DIM * I_DIM;
  unsigned short* y    = hbuf + (size_t)2 * T_TOK * I_DIM;

  hipMemsetAsync(ws, 0, 64, stream);                        // counts

  transposeAll_kernel<<<dim3(704, 1, 25), 256, 0, stream>>>(
      x, wr, wg, wu, wd, wgT, wuT, wdT, xb, cnt, tokL, sA, sB, wA, wB);
  scan_kernel<<<1, 64, 0, stream>>>(cnt, offs);
  gateup_kernel<<<dim3(I_DIM / 128, CAP / 128, NEXP), 256, 0, stream>>>(
      xb, wgT, wuT, cnt, offs, tokL, hbuf);
  down_kernel<<<dim3(H_DIM / 128, CAP / 128, NEXP), 256, 0, stream>>>(
      hbuf, wdT, cnt, offs, y);
  combine_kernel<<<T_TOK, 256, 0, stream>>>(y, offs, sA, sB, wA, wB, out);
}